// Round 15
// baseline (218.259 us; speedup 1.0000x reference)
//
#include <hip/hip_runtime.h>

// ---- problem constants ----
// B=2, S=1024, P=1024, D=2048, H=16, DH=128, T=P+S=2048
#define SOFT_SCALE 0.08838834764831845f   // 1/sqrt(128)
#define QSCALE     0.12751741f            // SOFT_SCALE * log2(e)  (exp2-domain softmax)
#define DEFER_THR  11.544f                // 8 * log2(e)
#define BSD 4194304                        // B*S*D
#define NELEM 4194304                      // elements per [B,S,D] tensor

typedef __attribute__((ext_vector_type(4))) float    f32x4;
typedef __attribute__((ext_vector_type(8))) short    bf16x8;
typedef __attribute__((ext_vector_type(4))) short    bf16x4;
typedef __attribute__((ext_vector_type(4))) unsigned u32x4;

__device__ __forceinline__ float bs2f(short s) {
    unsigned u = ((unsigned)(unsigned short)s) << 16;
    return __builtin_bit_cast(float, u);
}
__device__ __forceinline__ short f2bs(float f) {
    unsigned u = __builtin_bit_cast(unsigned, f);
    unsigned r = (u + 0x7fffu + ((u >> 16) & 1u)) >> 16;
    return (short)r;
}

// async global->LDS, 16B per lane (wave-uniform LDS base + lane*16)
__device__ __forceinline__ void stage16(const short* g, short* l) {
#if __has_builtin(__builtin_amdgcn_global_load_lds)
    __builtin_amdgcn_global_load_lds(
        (const __attribute__((address_space(1))) void*)g,
        (__attribute__((address_space(3))) void*)l, 16, 0, 0);
#else
    *(bf16x8*)l = *(const bf16x8*)g;
#endif
}

// ---------------------------------------------------------------------------
// probe: decide whether past_k_q device buffer is int32 or int8, init scalars
// ---------------------------------------------------------------------------
__global__ void probe_init(const int* __restrict__ q, float* __restrict__ scal) {
    const int lane = threadIdx.x;
    int bad = 0;
#pragma unroll
    for (int i = 0; i < 4; ++i) {
        const int v = q[i * 64 + lane];
        bad |= (v < -128 || v > 127) ? 1 : 0;
    }
    const int anybad = __any(bad);
    if (lane == 0) ((int*)scal)[2] = anybad ? 0 : 1;  // 1 => int32, 0 => int8
    if (lane == 1) scal[0] = 0.f;
    if (lane == 2) scal[1] = 0.f;
}

// ---------------------------------------------------------------------------
// prep: z=0 f32->bf16 conv of hidden_states; z=1/2 dequant past K/V into
// K_full/V_full rows [b*2048 .. b*2048+1024)
// ---------------------------------------------------------------------------
__global__ void prep_kernel(const float* __restrict__ X, short* __restrict__ Y,
                            const void* __restrict__ pk, const void* __restrict__ pv,
                            const float* __restrict__ psk, const float* __restrict__ psv,
                            short* __restrict__ Kf, short* __restrict__ Vf,
                            const int* __restrict__ wsflag) {
    const int z = blockIdx.z;
    const int stride = gridDim.x * blockDim.x;
    if (z == 0) {
        for (int i = blockIdx.x * blockDim.x + threadIdx.x; i < NELEM / 8; i += stride) {
            const int e = i * 8;
            f32x4 a = *(const f32x4*)&X[e];
            f32x4 b = *(const f32x4*)&X[e + 4];
            bf16x8 o;
            o[0] = f2bs(a[0]); o[1] = f2bs(a[1]); o[2] = f2bs(a[2]); o[3] = f2bs(a[3]);
            o[4] = f2bs(b[0]); o[5] = f2bs(b[1]); o[6] = f2bs(b[2]); o[7] = f2bs(b[3]);
            *(bf16x8*)&Y[e] = o;
        }
    } else {
        const void* src = (z == 2) ? pv : pk;
        const float sc = (z == 2) ? *psv : *psk;
        short* dst = (z == 2) ? Vf : Kf;
        const int flag = wsflag[2];
        for (int i = blockIdx.x * blockDim.x + threadIdx.x; i < NELEM / 8; i += stride) {
            const int e = i * 8;
            int vals[8];
            if (flag) {
                const int* s = (const int*)src + e;
                *(int4*)&vals[0] = *(const int4*)&s[0];
                *(int4*)&vals[4] = *(const int4*)&s[4];
            } else {
                const int2 wv = *(const int2*)((const char*)src + e);
#pragma unroll
                for (int j = 0; j < 4; ++j) vals[j] = (int)(signed char)(wv.x >> (8 * j));
#pragma unroll
                for (int j = 0; j < 4; ++j) vals[4 + j] = (int)(signed char)(wv.y >> (8 * j));
            }
            bf16x8 o;
#pragma unroll
            for (int j = 0; j < 8; ++j) o[j] = f2bs((float)vals[j] * sc);
            *(bf16x8*)&dst[e + ((e >> 21) << 21)] = o;
        }
    }
}

// ---------------------------------------------------------------------------
// W[k][n] f32 -> WT[n][k] bf16, up to 4 weights batched over grid.z
// ---------------------------------------------------------------------------
__global__ __launch_bounds__(256) void transpose_conv(const float* __restrict__ W0,
                                                      const float* __restrict__ W1,
                                                      const float* __restrict__ W2,
                                                      const float* __restrict__ W3,
                                                      short* __restrict__ WT) {
    __shared__ __align__(16) short Tl[64 * 68];
    const float* W = blockIdx.z == 0 ? W0 : (blockIdx.z == 1 ? W1 :
                     (blockIdx.z == 2 ? W2 : W3));
    short* out = WT + (long)blockIdx.z * 4194304;
    const int tid = threadIdx.x;
    const int n0 = blockIdx.x * 64, k0 = blockIdx.y * 64;
#pragma unroll
    for (int i = 0; i < 4; ++i) {
        const int e = i * 1024 + tid * 4;
        const int r = e >> 6, c = e & 63;
        f32x4 f = *(const f32x4*)&W[(long)(k0 + r) * 2048 + n0 + c];
        bf16x4 s4 = { f2bs(f[0]), f2bs(f[1]), f2bs(f[2]), f2bs(f[3]) };
        *(bf16x4*)&Tl[r * 68 + c] = s4;
    }
    __syncthreads();
#pragma unroll
    for (int i = 0; i < 4; ++i) {
        const int e = i * 1024 + tid * 4;
        const int nr = e >> 6, kk = e & 63;
        bf16x4 o = { Tl[(kk + 0) * 68 + nr], Tl[(kk + 1) * 68 + nr],
                     Tl[(kk + 2) * 68 + nr], Tl[(kk + 3) * 68 + nr] };
        *(bf16x4*)&out[(long)(n0 + nr) * 2048 + k0 + kk] = o;
    }
}

// ---------------------------------------------------------------------------
// QKV GEMM, 256x256 tile, BK=32, 8 waves, fine-interleaved deep pipeline
// (R12/R14-measured-best). Single barrier per K-step; 32B-granule
// sector-preserving LDS swizzle (conflicts == 0); counted vmcnt(8);
// fused absmax for K/V slices in the epilogue.
// grid 8x8x3 (XCD swizzled): z0 Q bf16*QSCALE, z1/z2 K/V concat remap + amax.
// ---------------------------------------------------------------------------
__global__ __launch_bounds__(512, 2) void gemm_qkv8(
    const short* __restrict__ A,
    const short* __restrict__ Bt0, const short* __restrict__ Bt1, const short* __restrict__ Bt2,
    const float* __restrict__ bi0, const float* __restrict__ bi1, const float* __restrict__ bi2,
    void* __restrict__ o0, void* __restrict__ o1, void* __restrict__ o2,
    float* __restrict__ scal) {
    __shared__ __align__(16) short L[4][16384];   // per buf: A [0,8192), B [8192,16384)

    const int orig = blockIdx.x + 8 * (blockIdx.y + 8 * blockIdx.z);
    int swz = (orig & 7) * 24 + (orig >> 3);      // 192 % 8 == 0
    const int bx = swz & 7; swz >>= 3;
    const int by = swz & 7;
    const int bz = swz >> 3;

    const short* Bt   = bz == 0 ? Bt0 : (bz == 1 ? Bt1 : Bt2);
    const float* bias = bz == 0 ? bi0 : (bz == 1 ? bi1 : bi2);
    void* outp        = bz == 0 ? o0  : (bz == 1 ? o1  : o2);
    const int mode    = (bz == 0) ? 1 : 2;
    const float scl   = (bz == 0) ? QSCALE : 1.f;

    const int tid = threadIdx.x, lane = tid & 63, w = tid >> 6;
    const int wm = w >> 2, wn = w & 3;            // 2(M) x 4(N) waves
    const int l4 = lane >> 4, ln = lane & 15;
    const int m0 = by * 256, n0 = bx * 256;

    // staging: rows {tid>>2, +128}; SOURCE column 32B-granule swizzled
    const int scol = (((tid & 3) ^ (((tid >> 5) & 1) << 1))) * 8;
    const short* gA = A  + (long)(m0 + (tid >> 2)) * 2048 + scol;
    const short* gB = Bt + (long)(n0 + (tid >> 2)) * 2048 + scol;

#define ISSUE_A(t)                                                        \
    do {                                                                  \
        const long ko = (long)(t) * 32;                                   \
        stage16(gA + ko,              &L[(t) & 3][tid * 8]);              \
        stage16(gA + ko + 128 * 2048, &L[(t) & 3][4096 + tid * 8]);       \
    } while (0)
#define ISSUE_B(t)                                                        \
    do {                                                                  \
        const long ko = (long)(t) * 32;                                   \
        stage16(gB + ko,              &L[(t) & 3][8192 + tid * 8]);       \
        stage16(gB + ko + 128 * 2048, &L[(t) & 3][12288 + tid * 8]);      \
    } while (0)

    // read-side slot (same involution; row bit3 at read time = ln bit3)
    const int rsl = (l4 ^ ((ln >> 3) << 1)) * 8;

    f32x4 acc[8][4];
#pragma unroll
    for (int mi = 0; mi < 8; ++mi)
#pragma unroll
        for (int ni = 0; ni < 4; ++ni) acc[mi][ni] = (f32x4){0, 0, 0, 0};

    // prologue: tiles 0,1,2 in flight (12 loads/lane outstanding max)
    ISSUE_A(0); ISSUE_B(0);
    ISSUE_A(1); ISSUE_B(1);
    ISSUE_A(2); ISSUE_B(2);

    for (int t = 0; t < 64; ++t) {
        if (t < 62)       asm volatile("s_waitcnt vmcnt(8)" ::: "memory");
        else if (t == 62) asm volatile("s_waitcnt vmcnt(4)" ::: "memory");
        else              asm volatile("s_waitcnt vmcnt(0)" ::: "memory");
        __builtin_amdgcn_s_barrier();   // tile t visible; buf[(t+3)&3] readers retired
        const int c = t & 3;
        const short* Ab = &L[c][0];
        const short* Bb = &L[c][8192];

        // phase 0: B frags + A frags (mh=0), issue A-stage, 16 MFMA
        bf16x8 bf[4], af[4];
#pragma unroll
        for (int fn = 0; fn < 4; ++fn)
            bf[fn] = *(const bf16x8*)&Bb[(wn * 64 + fn * 16 + ln) * 32 + rsl];
#pragma unroll
        for (int fm = 0; fm < 4; ++fm)
            af[fm] = *(const bf16x8*)&Ab[(wm * 128 + fm * 16 + ln) * 32 + rsl];
        if (t + 3 < 64) ISSUE_A(t + 3);
        __builtin_amdgcn_s_setprio(1);
#pragma unroll
        for (int fm = 0; fm < 4; ++fm)
#pragma unroll
            for (int fn = 0; fn < 4; ++fn)
                acc[fm][fn] = __builtin_amdgcn_mfma_f32_16x16x32_bf16(
                    af[fm], bf[fn], acc[fm][fn], 0, 0, 0);
        __builtin_amdgcn_s_setprio(0);

        // phase 1 (no barrier): A frags (mh=1), issue B-stage, 16 MFMA
        bf16x8 af2[4];
#pragma unroll
        for (int fm = 0; fm < 4; ++fm)
            af2[fm] = *(const bf16x8*)&Ab[(wm * 128 + 64 + fm * 16 + ln) * 32 + rsl];
        if (t + 3 < 64) ISSUE_B(t + 3);
        __builtin_amdgcn_s_setprio(1);
#pragma unroll
        for (int fm = 0; fm < 4; ++fm)
#pragma unroll
            for (int fn = 0; fn < 4; ++fn)
                acc[4 + fm][fn] = __builtin_amdgcn_mfma_f32_16x16x32_bf16(
                    af2[fm], bf[fn], acc[4 + fm][fn], 0, 0, 0);
        __builtin_amdgcn_s_setprio(0);
    }
#undef ISSUE_A
#undef ISSUE_B

    // epilogue + fused absmax (K/V slices)
    float amax = 0.f;
#pragma unroll
    for (int fn = 0; fn < 4; ++fn) {
        const int gn = n0 + wn * 64 + fn * 16 + ln;
        const float bv = bias[gn];
#pragma unroll
        for (int fm = 0; fm < 8; ++fm) {
#pragma unroll
            for (int r = 0; r < 4; ++r) {
                const int gm = m0 + wm * 128 + fm * 16 + l4 * 4 + r;
                const float v = (acc[fm][fn][r] + bv) * scl;
                if (mode == 1) {
                    ((short*)outp)[(long)gm * 2048 + gn] = f2bs(v);
                } else {
                    amax = fmaxf(amax, fabsf(v));
                    const int gr = gm + 1024 + ((gm >> 10) << 10);  // b*2048+1024+s
                    ((short*)outp)[(long)gr * 2048 + gn] = f2bs(v);
                }
            }
        }
    }
    if (mode == 2) {
#pragma unroll
        for (int o = 32; o > 0; o >>= 1) amax = fmaxf(amax, __shfl_xor(amax, o));
        if (lane == 0)
            atomicMax((unsigned int*)&scal[bz - 1], __builtin_bit_cast(unsigned int, amax));
    }
}

// ---------------------------------------------------------------------------
// GEMM (fallback path): R2 structure, 128x128, 2-phase, linear loads.
// mode: 0 = f32 plain, 1 = bf16 plain, 2 = bf16 concat row-remap
// ---------------------------------------------------------------------------
__global__ __launch_bounds__(256, 2) void gemm_m97(
    const short* __restrict__ A, const short* __restrict__ Bt,
    const float* __restrict__ bias, void* __restrict__ outp,
    int mode, float scl) {
    __shared__ __align__(16) short Al[2][4096];
    __shared__ __align__(16) short Bl[2][4096];
    const int nbx = gridDim.x, nby = gridDim.y;
    const int nwg = nbx * nby;
    const int orig = blockIdx.x + nbx * blockIdx.y;
    const int cpx = nwg >> 3;
    int swz = (orig & 7) * cpx + (orig >> 3);
    const int bx = swz % nbx;
    const int by = swz / nbx;

    const int tid = threadIdx.x, lane = tid & 63, w = tid >> 6;
    const int wm = w >> 1, wn = w & 1, l4 = lane >> 4, ln = lane & 15;
    const int m0 = by * 128, n0 = bx * 128;

    const short* gA0 = A  + (long)(m0 + (tid >> 2)) * 2048 + (tid & 3) * 8;
    const short* gA1 = gA0 + 64 * 2048;
    const short* gB0 = Bt + (long)(n0 + (tid >> 2)) * 2048 + (tid & 3) * 8;
    const short* gB1 = gB0 + 64 * 2048;

    f32x4 acc[4][4];
#pragma unroll
    for (int mi = 0; mi < 4; ++mi)
#pragma unroll
        for (int ni = 0; ni < 4; ++ni) acc[mi][ni] = (f32x4){0, 0, 0, 0};

#define STAGE_G(buf, ko)                                   \
    do {                                                   \
        stage16(gA0 + (ko), &Al[buf][tid * 8]);            \
        stage16(gA1 + (ko), &Al[buf][2048 + tid * 8]);     \
        stage16(gB0 + (ko), &Bl[buf][tid * 8]);            \
        stage16(gB1 + (ko), &Bl[buf][2048 + tid * 8]);     \
    } while (0)

    STAGE_G(0, 0);
    asm volatile("s_waitcnt vmcnt(0)" ::: "memory");
    __syncthreads();
    int cur = 0;
    for (int kt = 0; kt < 64; ++kt) {
        if (kt < 63) STAGE_G(cur ^ 1, (kt + 1) * 32);
        bf16x8 af[4], bfr[4];
#pragma unroll
        for (int mi = 0; mi < 4; ++mi)
            af[mi] = *(const bf16x8*)&Al[cur][(wm * 64 + mi * 16 + ln) * 32 + l4 * 8];
#pragma unroll
        for (int ni = 0; ni < 4; ++ni)
            bfr[ni] = *(const bf16x8*)&Bl[cur][(wn * 64 + ni * 16 + ln) * 32 + l4 * 8];
#pragma unroll
        for (int mi = 0; mi < 4; ++mi)
#pragma unroll
            for (int ni = 0; ni < 4; ++ni)
                acc[mi][ni] = __builtin_amdgcn_mfma_f32_16x16x32_bf16(
                    af[mi], bfr[ni], acc[mi][ni], 0, 0, 0);
        asm volatile("s_waitcnt vmcnt(0)" ::: "memory");
        __syncthreads();
        cur ^= 1;
    }
#undef STAGE_G

#pragma unroll
    for (int ni = 0; ni < 4; ++ni) {
        const int gn = n0 + wn * 64 + ni * 16 + ln;
        const float bv = bias[gn];
#pragma unroll
        for (int mi = 0; mi < 4; ++mi) {
#pragma unroll
            for (int r = 0; r < 4; ++r) {
                const int gm = m0 + wm * 64 + mi * 16 + l4 * 4 + r;
                const float v = (acc[mi][ni][r] + bv) * scl;
                if (mode == 0) {
                    ((float*)outp)[(long)gm * 2048 + gn] = v;
                } else if (mode == 1) {
                    ((short*)outp)[(long)gm * 2048 + gn] = f2bs(v);
                } else {
                    const int gr = gm + 1024 + ((gm >> 10) << 10);
                    ((short*)outp)[(long)gr * 2048 + gn] = f2bs(v);
                }
            }
        }
    }
}

// ---------------------------------------------------------------------------
// Wo GEMM: 128(M) x 64(N) tile -> grid 32x16 = 512 blocks = 2 blocks/CU.
// ---------------------------------------------------------------------------
__global__ __launch_bounds__(256, 2) void gemm_wo(const short* __restrict__ A,
                                                  const short* __restrict__ Bt,
                                                  const float* __restrict__ bias,
                                                  float* __restrict__ outp) {
    __shared__ __align__(16) short Al[2][4096];
    __shared__ __align__(16) short Bl[2][2048];
    const int orig = blockIdx.x + 32 * blockIdx.y;
    const int swz = (orig & 7) * 64 + (orig >> 3);   // 512 % 8 == 0
    const int bx = swz & 31, by = swz >> 5;
    const int tid = threadIdx.x, lane = tid & 63, w = tid >> 6;
    const int wm = w >> 1, wn = w & 1, l4 = lane >> 4, ln = lane & 15;
    const int m0 = by * 128, n0 = bx * 64;

    const short* gA0 = A  + (long)(m0 + (tid >> 2)) * 2048 + (tid & 3) * 8;
    const short* gA1 = gA0 + 64 * 2048;
    const short* gB0 = Bt + (long)(n0 + (tid >> 2)) * 2048 + (tid & 3) * 8;

    f32x4 acc[4][2];
#pragma unroll
    for (int mi = 0; mi < 4; ++mi)
#pragma unroll
        for (int ni = 0; ni < 2; ++ni) acc[mi][ni] = (f32x4){0, 0, 0, 0};

#define STAGE_W(buf, ko)                                   \
    do {                                                   \
        stage16(gA0 + (ko), &Al[buf][tid * 8]);            \
        stage16(gA1 + (ko), &Al[buf][2048 + tid * 8]);     \
        stage16(gB0 + (ko), &Bl[buf][tid * 8]);            \
    } while (0)

    STAGE_W(0, 0);
    asm volatile("s_waitcnt vmcnt(0)" ::: "memory");
    __syncthreads();
    int cur = 0;
    for (int kt = 0; kt < 64; ++kt) {
        if (kt < 63) STAGE_W(cur ^ 1, (kt + 1) * 32);
        bf16x8 af[4], bfr[2];
#pragma unroll
        for (int mi = 0; mi < 4; ++mi)
            af[mi] = *(const bf16x8*)&Al[cur][(wm * 64 + mi * 16 + ln) * 32 + l4 * 8];
#pragma unroll
        for (int ni = 0; ni < 2; ++ni)
            bfr[ni] = *(const bf16x8*)&Bl[cur][(wn * 32 + ni * 16 + ln) * 32 + l4 * 8];
#pragma unroll
        for (int mi = 0; mi < 4; ++mi)
#pragma unroll
            for (int ni = 0; ni < 2; ++ni)
                acc[mi][ni] = __builtin_amdgcn_mfma_f32_16x16x32_bf16(
                    af[mi], bfr[ni], acc[mi][ni], 0, 0, 0);
        asm volatile("s_waitcnt vmcnt(0)" ::: "memory");
        __syncthreads();
        cur ^= 1;
    }
#undef STAGE_W

#pragma unroll
    for (int ni = 0; ni < 2; ++ni) {
        const int gn = n0 + wn * 32 + ni * 16 + ln;
        const float bv = bias[gn];
#pragma unroll
        for (int mi = 0; mi < 4; ++mi) {
#pragma unroll
            for (int r = 0; r < 4; ++r) {
                const int gm = m0 + wm * 64 + mi * 16 + l4 * 4 + r;
                outp[(long)gm * 2048 + gn] = acc[mi][ni][r] + bv;
            }
        }
    }
}

// ---------------------------------------------------------------------------
// absmax (fallback path only)
// ---------------------------------------------------------------------------
__global__ void absmax_kernel(const short* __restrict__ Kf, const short* __restrict__ Vf,
                              float* __restrict__ scal) {
    const int z = blockIdx.z;
    const short* src = z ? Vf : Kf;
    const int tid = threadIdx.x, lane = tid & 63, w = tid >> 6;
    float mx = 0.f;
    const int stride = gridDim.x * blockDim.x;
    for (int i = blockIdx.x * blockDim.x + tid; i < NELEM / 8; i += stride) {
        const int e = i * 8;
        const int flat = e + 2097152 + ((e >> 21) << 21);
        bf16x8 v = *(const bf16x8*)&src[flat];
#pragma unroll
        for (int j = 0; j < 8; ++j) mx = fmaxf(mx, fabsf(bs2f(v[j])));
    }
#pragma unroll
    for (int o = 32; o > 0; o >>= 1) mx = fmaxf(mx, __shfl_xor(mx, o));
    __shared__ float wred[4];
    if (lane == 0) wred[w] = mx;
    __syncthreads();
    if (tid == 0) {
        const float m2 = fmaxf(fmaxf(wred[0], wred[1]), fmaxf(wred[2], wred[3]));
        atomicMax((unsigned int*)&scal[z], __builtin_bit_cast(unsigned int, m2));
    }
}

// ---------------------------------------------------------------------------
// quantize new-KV region -> d_out (as floats), plus the two scale scalars
// (x8 vectorized)
// ---------------------------------------------------------------------------
__global__ void quantize_kernel(const short* __restrict__ Kf, const short* __restrict__ Vf,
                                const float* __restrict__ scal, float* __restrict__ out) {
    const int z = blockIdx.z;
    const short* src = z ? Vf : Kf;
    const float mx = scal[z];
    const float scale = mx * (1.f / 127.f);
    const float inv = (mx > 0.f) ? 127.f / mx : 0.f;
    const long ob = z ? (2L * BSD + 1) : (1L * BSD);
    if (blockIdx.x == 0 && threadIdx.x == 0)
        out[z ? (3L * BSD + 1) : (2L * BSD)] = scale;
    const int stride = gridDim.x * blockDim.x;
    for (int i = blockIdx.x * blockDim.x + threadIdx.x; i < NELEM / 8; i += stride) {
        const int e = i * 8;
        const int flat = e + 2097152 + ((e >> 21) << 21);
        bf16x8 x8 = *(const bf16x8*)&src[flat];
        float4 q0, q1;
        q0.x = fminf(127.f, fmaxf(-128.f, rintf(bs2f(x8[0]) * inv)));
        q0.y = fminf(127.f, fmaxf(-128.f, rintf(bs2f(x8[1]) * inv)));
        q0.z = fminf(127.f, fmaxf(-128.f, rintf(bs2f(x8[2]) * inv)));
        q0.w = fminf(127.f, fmaxf(-128.f, rintf(bs2f(x8[3]) * inv)));
        q1.x = fminf(127.f, fmaxf(-128.f, rintf(bs2f(x8[4]) * inv)));
        q1.y = fminf(127.f, fmaxf(-128.f, rintf(bs2f(x8[5]) * inv)));
        q1.z = fminf(127.f, fmaxf(-128.f, rintf(bs2f(x8[6]) * inv)));
        q1.w = fminf(127.f, fmaxf(-128.f, rintf(bs2f(x8[7]) * inv)));
        *(float4*)&out[ob + e] = q0;
        *(float4*)&out[ob + e + 4] = q1;
    }
}

// ---------------------------------------------------------------------------
// flash attention, double-buffered LDS, exp2-domain softmax, T15 pipeline:
// QK^T(t+1) is computed BEFORE softmax(t), so its MFMAs overlap softmax's
// VALU chain. Both LDS buffers are primed in the prologue; tile t+2 is
// written into buf[t&1] after PV(t) retires (extra barrier).
// ---------------------------------------------------------------------------
__global__ __launch_bounds__(256, 2) void attn_kernel(const short* __restrict__ Q,
                                                      const short* __restrict__ Kf,
                                                      const short* __restrict__ Vf,
                                                      short* __restrict__ O) {
    __shared__ __align__(16) short Kl[2][64 * 136];   // 34.0 KB
    __shared__ __align__(16) short Vt[2][128 * 72];   // 36.0 KB
    const int L = blockIdx.x + 16 * (blockIdx.y + 16 * blockIdx.z);
    const int x = L & 7, rr = L >> 3;
    const int qt0 = rr & 15, pgrp = rr >> 4;
    const int p = x + 8 * pgrp;
    const int h = p >> 1, b = p & 1;
    const int qt = (pgrp >= 2) ? (15 - qt0) : qt0;

    const int tid = threadIdx.x, w = tid >> 6, lane = tid & 63;
    const int l4 = lane >> 4, n = lane & 15;
    const int rg = tid >> 4, cg = tid & 15, stc = cg * 8;
    const int sIdx = qt * 64 + w * 16 + n;
    const int qlim = 1024 + sIdx;

    bf16x8 qf[4];
#pragma unroll
    for (int c = 0; c < 4; ++c)
        qf[c] = *(const bf16x8*)&Q[(long)(b * 1024 + sIdx) * 2048 + h * 128 + c * 32 + l4 * 8];

    f32x4 acco[8];
#pragma unroll
    for (int i = 0; i < 8; ++i) acco[i] = (f32x4){0, 0, 0, 0};
    float m_run = 0.f, l_run = 0.f;

    const short* Kb = Kf + (long)(b * 2048) * 2048 + h * 128;
    const short* Vb = Vf + (long)(b * 2048) * 2048 + h * 128;
    const int nt = 17 + qt;    // always >= 17

    bf16x8 kreg[4], vreg[4];
#define LOAD_KV(te)                                                                   \
    do {                                                                              \
        _Pragma("unroll")                                                             \
        for (int i = 0; i < 4; ++i)                                                   \
            kreg[i] = *(const bf16x8*)&Kb[(long)((te) + i * 16 + rg) * 2048 + stc];   \
        _Pragma("unroll")                                                             \
        for (int i = 0; i < 4; ++i)                                                   \
            vreg[i] = *(const bf16x8*)&Vb[(long)((te) + rg * 4 + i) * 2048 + stc];    \
    } while (0)
#define WRITE_BUF(bf)                                                                 \
    do {                                                                              \
        _Pragma("unroll")                                                             \
        for (int i = 0; i < 4; ++i)                                                   \
            *(bf16x8*)&Kl[bf][(i * 16 + rg) * 136 + stc] = kreg[i];                   \
        _Pragma("unroll")                                                             \
        for (int j = 0; j < 8; ++j) {                                                 \
            const int d = stc + j;                                                    \
            bf16x4 c4 = { vreg[0][j], vreg[1][j], vreg[2][j], vreg[3][j] };           \
            *(bf16x4*)&Vt[bf][d * 72 + ((rg ^ ((d >> 3) & 7)) << 2)] = c4;            \
        }                                                                             \
    } while (0)

// compute raw scores for tile tt from buffer bb into pd[16], with causal mask
#define QK_TILE(pd, bb, tt)                                                            \
    do {                                                                               \
        __builtin_amdgcn_s_setprio(1);                                                 \
        _Pragma("unroll")                                                              \
        for (int kt = 0; kt < 4; ++kt) {                                               \
            f32x4 sc4 = (f32x4){0, 0, 0, 0};                                           \
            _Pragma("unroll")                                                          \
            for (int c = 0; c < 4; ++c) {                                              \
                bf16x8 kfr = *(const bf16x8*)&Kl[bb][(kt * 16 + n) * 136 + c * 32 + l4 * 8]; \
                sc4 = __builtin_amdgcn_mfma_f32_16x16x32_bf16(kfr, qf[c], sc4, 0, 0, 0);     \
            }                                                                          \
            _Pragma("unroll")                                                          \
            for (int r = 0; r < 4; ++r) pd[kt * 4 + r] = sc4[r];                       \
        }                                                                              \
        __builtin_amdgcn_s_setprio(0);                                                 \
        if ((tt) >= 16) {                                                              \
            _Pragma("unroll")                                                          \
            for (int i = 0; i < 16; ++i) {                                             \
                const int kg = (tt) * 64 + (i >> 2) * 16 + l4 * 4 + (i & 3);           \
                if (kg > qlim) pd[i] = -1e30f;                                         \
            }                                                                          \
        }                                                                              \
    } while (0)

    // prologue: prime both buffers, compute QK(0)
    LOAD_KV(0);
    WRITE_BUF(0);
    __syncthreads();
    LOAD_KV(64);          // nt >= 17, tile 1 always exists
    WRITE_BUF(1);
    __syncthreads();

    float pA[16], pB[16];
    QK_TILE(pA, 0, 0);

    for (int t = 0; t < nt; ++t) {
        const int buf = t & 1;
        float* pc = (t & 1) ? pB : pA;    // current tile's raw scores
        float* pn = (t & 1) ? pA : pB;    // next tile's scores (to fill)

        if (t + 2 < nt) LOAD_KV((t + 2) * 64);   // global loads, land under compute

        // QK^T(t+1) on MFMA pipe -- overlaps the softmax VALU chain below
        if (t + 1 < nt) QK_TILE(pn, buf ^ 1, t + 1);

        // softmax(t) on VALU
        float tmax = fmaxf(pc[0], pc[1]);
#pragma unroll
        for (int i = 2; i < 16; ++i) tmax = fmaxf(tmax, pc[i]);
        tmax = fmaxf(tmax, __shfl_xor(tmax, 16));
        tmax = fmaxf(tmax, __shfl_xor(tmax, 32));
        float e16[16], ps[4] = {0.f, 0.f, 0.f, 0.f};
#pragma unroll
        for (int i = 0; i < 16; ++i) { e16[i] = exp2f(pc[i] - m_run); ps[i & 3] += e16[i]; }
        float tsum = (ps[0] + ps[1]) + (ps[2] + ps[3]);
        if (!__all(tmax <= m_run + DEFER_THR)) {
            const float mnew = fmaxf(m_run, tmax);
            const float fac = exp2f(m_run - mnew);
            tsum *= fac;
#pragma unroll
            for (int i = 0; i < 16; ++i) e16[i] *= fac;
            l_run *= fac;
#pragma unroll
            for (int i = 0; i < 8; ++i) acco[i] *= fac;
            m_run = mnew;
        }
        tsum += __shfl_xor(tsum, 16);
        tsum += __shfl_xor(tsum, 32);
        l_run += tsum;

        u32x4 pw0, pw1;
#pragma unroll
        for (int wd = 0; wd < 4; ++wd) {
            unsigned r0, r1;
            asm("v_cvt_pk_bf16_f32 %0, %1, %2" : "=v"(r0) : "v"(e16[2 * wd]), "v"(e16[2 * wd + 1]));
            asm("v_cvt_pk_bf16_f32 %0, %1, %2" : "=v"(r1) : "v"(e16[8 + 2 * wd]), "v"(e16[8 + 2 * wd + 1]));
            pw0[wd] = r0; pw1[wd] = r1;
        }
        bf16x8 pb[2] = { __builtin_bit_cast(bf16x8, pw0), __builtin_bit_cast(bf16x8, pw1) };

        // PV(t)
        __builtin_amdgcn_s_setprio(1);
#pragma unroll
        for (int dc = 0; dc < 8; ++dc) {
            const int d = dc * 16 + n;
            const int swd = ((d >> 3) & 7) << 2;
#pragma unroll
            for (int k32 = 0; k32 < 2; ++k32) {
                bf16x4 g0 = *(const bf16x4*)&Vt[buf][d * 72 + (k32 * 32 + ((4 * l4) ^ swd))];
                bf16x4 g1 = *(const bf16x4*)&Vt[buf][d * 72 + (k32 * 32 + ((16 + 4 * l4) ^ swd))];
                bf16x8 vf = { g0[0], g0[1], g0[2], g0[3], g1[0], g1[1], g1[2], g1[3] };
                acco[dc] = __builtin_amdgcn_mfma_f32_16x16x32_bf16(vf, pb[k32], acco[dc], 0, 0, 0);
            }
        }
        __builtin_amdgcn_s_setprio(0);

        if (t + 2 < nt) {
            __syncthreads();          // all waves done reading buf[t&1] (QK t+1 used buf^1)
            WRITE_BUF(buf);           // tile t+2 -> buf[t&1]
        }
        __syncthreads();              // buf writes visible before next iter's QK/PV
    }
#undef LOAD_KV
#undef WRITE_BUF
#undef QK_TILE

    const float inv = 1.f / l_run;
#pragma unroll
    for (int dc = 0; dc < 8; ++dc)
#pragma unroll
        for (int r = 0; r < 4; ++r)
            Kl[0][(w * 16 + n) * 136 + dc * 16 + l4 * 4 + r] = f2bs(acco[dc][r] * inv);
    __syncthreads();
#pragma unroll
    for (int i = 0; i < 4; ++i) {
        const int row = i * 4 + (lane >> 4);
        const int col = (lane & 15) * 8;
        bf16x8 ov = *(const bf16x8*)&Kl[0][(w * 16 + row) * 136 + col];
        *(bf16x8*)&O[(long)(b * 1024 + qt * 64 + w * 16 + row) * 2048 + h * 128 + col] = ov;
    }
}

// ---------------------------------------------------------------------------
extern "C" void kernel_launch(void* const* d_in, const int* in_sizes, int n_in,
                              void* d_out, int out_size, void* d_ws, size_t ws_size,
                              hipStream_t stream) {
    const float* h   = (const float*)d_in[0];
    const float* Wq  = (const float*)d_in[1];
    const float* bq  = (const float*)d_in[2];
    const float* Wk  = (const float*)d_in[3];
    const float* bk  = (const float*)d_in[4];
    const float* Wv  = (const float*)d_in[5];
    const float* bv  = (const float*)d_in[6];
    const float* Wo  = (const float*)d_in[7];
    const float* bo  = (const float*)d_in[8];
    const void*  pkq = d_in[9];
    const float* pks = (const float*)d_in[10];
    const void*  pvq = d_in[11];
    const float* pvs = (const float*)d_in[12];
    float* out = (float*)d_out;

    char* ws = (char*)d_ws;
    dim3 blk(256);

    if (ws_size >= 83886336ull) {
        float* scal  = (float*)ws;
        short* hbf   = (short*)(ws + 256);
        short* WT4   = (short*)(ws + 256 + 1L * 8388608);
        short* Qbf   = (short*)(ws + 256 + 5L * 8388608);
        short* Kfull = (short*)(ws + 256 + 6L * 8388608);
        short* Vfull = (short*)(ws + 256 + 6L * 8388608 + 16777216);
        short* attnb = hbf;

        probe_init<<<1, 64, 0, stream>>>((const int*)pkq, scal);
        prep_kernel<<<dim3(256, 1, 3), blk, 0, stream>>>(h, hbf, pkq, pvq, pks, pvs,
                                                         Kfull, Vfull, (const int*)d_ws);
        transpose_conv<<<dim3(32, 32, 4), blk, 0, stream>>>(Wq, Wk, Wv, Wo, WT4);
        gemm_qkv8<<<dim3(8, 8, 3), dim3(512), 0, stream>>>(hbf, WT4, WT4 + 4194304,
                                                           WT4 + 8388608, bq, bk, bv,
                                                           Qbf, Kfull, Vfull, scal);
        quantize_kernel<<<dim3(256, 1, 2), blk, 0, stream>>>(Kfull, Vfull, scal, out);
        attn_kernel<<<dim3(16, 16, 2), blk, 0, stream>>>(Qbf, Kfull, Vfull, attnb);
        gemm_wo<<<dim3(32, 16), blk, 0, stream>>>(attnb, WT4 + 12582912, bo, out);
    } else {
        float* scal  = (float*)ws;
        short* hbf   = (short*)(ws + 256);
        short* WT    = (short*)(ws + 256 + 1L * 8388608);
        short* Qbf   = (short*)(ws + 256 + 2L * 8388608);
        short* Kfull = (short*)(ws + 256 + 3L * 8388608);
        short* Vfull = (short*)(ws + 256 + 3L * 8388608 + 16777216);
        short* attnb = hbf;

        probe_init<<<1, 64, 0, stream>>>((const int*)pkq, scal);
        prep_kernel<<<dim3(256, 1, 3), blk, 0, stream>>>(h, hbf, pkq, pvq, pks, pvs,
                                                         Kfull, Vfull, (const int*)d_ws);
        transpose_conv<<<dim3(32, 32, 1), blk, 0, stream>>>(Wk, Wk, Wk, Wk, WT);
        gemm_m97<<<dim3(16, 16), blk, 0, stream>>>(hbf, WT, bk, Kfull, 2, 1.f);
        transpose_conv<<<dim3(32, 32, 1), blk, 0, stream>>>(Wv, Wv, Wv, Wv, WT);
        gemm_m97<<<dim3(16, 16), blk, 0, stream>>>(hbf, WT, bv, Vfull, 2, 1.f);
        absmax_kernel<<<dim3(512, 1, 2), blk, 0, stream>>>(Kfull, Vfull, scal);
        quantize_kernel<<<dim3(256, 1, 2), blk, 0, stream>>>(Kfull, Vfull, scal, out);
        transpose_conv<<<dim3(32, 32, 1), blk, 0, stream>>>(Wq, Wq, Wq, Wq, WT);
        gemm_m97<<<dim3(16, 16), blk, 0, stream>>>(hbf, WT, bq, Qbf, 1, QSCALE);
        attn_kernel<<<dim3(16, 16, 2), blk, 0, stream>>>(Qbf, Kfull, Vfull, attnb);
        transpose_conv<<<dim3(32, 32, 1), blk, 0, stream>>>(Wo, Wo, Wo, Wo, WT);
        gemm_wo<<<dim3(32, 16), blk, 0, stream>>>(attnb, WT, bo, out);
    }
}

// Round 16
// 210.185 us; speedup vs baseline: 1.0384x; 1.0384x over previous
//
#include <hip/hip_runtime.h>

// ---- problem constants ----
// B=2, S=1024, P=1024, D=2048, H=16, DH=128, T=P+S=2048
#define SOFT_SCALE 0.08838834764831845f   // 1/sqrt(128)
#define QSCALE     0.12751741f            // SOFT_SCALE * log2(e)  (exp2-domain softmax)
#define DEFER_THR  11.544f                // 8 * log2(e)
#define BSD 4194304                        // B*S*D
#define NELEM 4194304                      // elements per [B,S,D] tensor

typedef __attribute__((ext_vector_type(4))) float    f32x4;
typedef __attribute__((ext_vector_type(8))) short    bf16x8;
typedef __attribute__((ext_vector_type(4))) short    bf16x4;
typedef __attribute__((ext_vector_type(4))) unsigned u32x4;

__device__ __forceinline__ float bs2f(short s) {
    unsigned u = ((unsigned)(unsigned short)s) << 16;
    return __builtin_bit_cast(float, u);
}
__device__ __forceinline__ short f2bs(float f) {
    unsigned u = __builtin_bit_cast(unsigned, f);
    unsigned r = (u + 0x7fffu + ((u >> 16) & 1u)) >> 16;
    return (short)r;
}

// async global->LDS, 16B per lane (wave-uniform LDS base + lane*16)
__device__ __forceinline__ void stage16(const short* g, short* l) {
#if __has_builtin(__builtin_amdgcn_global_load_lds)
    __builtin_amdgcn_global_load_lds(
        (const __attribute__((address_space(1))) void*)g,
        (__attribute__((address_space(3))) void*)l, 16, 0, 0);
#else
    *(bf16x8*)l = *(const bf16x8*)g;
#endif
}

// ---------------------------------------------------------------------------
// probe: decide whether past_k_q device buffer is int32 or int8, init scalars
// ---------------------------------------------------------------------------
__global__ void probe_init(const int* __restrict__ q, float* __restrict__ scal) {
    const int lane = threadIdx.x;
    int bad = 0;
#pragma unroll
    for (int i = 0; i < 4; ++i) {
        const int v = q[i * 64 + lane];
        bad |= (v < -128 || v > 127) ? 1 : 0;
    }
    const int anybad = __any(bad);
    if (lane == 0) ((int*)scal)[2] = anybad ? 0 : 1;  // 1 => int32, 0 => int8
    if (lane == 1) scal[0] = 0.f;
    if (lane == 2) scal[1] = 0.f;
}

// ---------------------------------------------------------------------------
// prep: z=0 f32->bf16 conv of hidden_states; z=1/2 dequant past K/V into
// K_full/V_full rows [b*2048 .. b*2048+1024)
// ---------------------------------------------------------------------------
__global__ void prep_kernel(const float* __restrict__ X, short* __restrict__ Y,
                            const void* __restrict__ pk, const void* __restrict__ pv,
                            const float* __restrict__ psk, const float* __restrict__ psv,
                            short* __restrict__ Kf, short* __restrict__ Vf,
                            const int* __restrict__ wsflag) {
    const int z = blockIdx.z;
    const int stride = gridDim.x * blockDim.x;
    if (z == 0) {
        for (int i = blockIdx.x * blockDim.x + threadIdx.x; i < NELEM / 8; i += stride) {
            const int e = i * 8;
            f32x4 a = *(const f32x4*)&X[e];
            f32x4 b = *(const f32x4*)&X[e + 4];
            bf16x8 o;
            o[0] = f2bs(a[0]); o[1] = f2bs(a[1]); o[2] = f2bs(a[2]); o[3] = f2bs(a[3]);
            o[4] = f2bs(b[0]); o[5] = f2bs(b[1]); o[6] = f2bs(b[2]); o[7] = f2bs(b[3]);
            *(bf16x8*)&Y[e] = o;
        }
    } else {
        const void* src = (z == 2) ? pv : pk;
        const float sc = (z == 2) ? *psv : *psk;
        short* dst = (z == 2) ? Vf : Kf;
        const int flag = wsflag[2];
        for (int i = blockIdx.x * blockDim.x + threadIdx.x; i < NELEM / 8; i += stride) {
            const int e = i * 8;
            int vals[8];
            if (flag) {
                const int* s = (const int*)src + e;
                *(int4*)&vals[0] = *(const int4*)&s[0];
                *(int4*)&vals[4] = *(const int4*)&s[4];
            } else {
                const int2 wv = *(const int2*)((const char*)src + e);
#pragma unroll
                for (int j = 0; j < 4; ++j) vals[j] = (int)(signed char)(wv.x >> (8 * j));
#pragma unroll
                for (int j = 0; j < 4; ++j) vals[4 + j] = (int)(signed char)(wv.y >> (8 * j));
            }
            bf16x8 o;
#pragma unroll
            for (int j = 0; j < 8; ++j) o[j] = f2bs((float)vals[j] * sc);
            *(bf16x8*)&dst[e + ((e >> 21) << 21)] = o;
        }
    }
}

// ---------------------------------------------------------------------------
// W[k][n] f32 -> WT[n][k] bf16, up to 4 weights batched over grid.z
// ---------------------------------------------------------------------------
__global__ __launch_bounds__(256) void transpose_conv(const float* __restrict__ W0,
                                                      const float* __restrict__ W1,
                                                      const float* __restrict__ W2,
                                                      const float* __restrict__ W3,
                                                      short* __restrict__ WT) {
    __shared__ __align__(16) short Tl[64 * 68];
    const float* W = blockIdx.z == 0 ? W0 : (blockIdx.z == 1 ? W1 :
                     (blockIdx.z == 2 ? W2 : W3));
    short* out = WT + (long)blockIdx.z * 4194304;
    const int tid = threadIdx.x;
    const int n0 = blockIdx.x * 64, k0 = blockIdx.y * 64;
#pragma unroll
    for (int i = 0; i < 4; ++i) {
        const int e = i * 1024 + tid * 4;
        const int r = e >> 6, c = e & 63;
        f32x4 f = *(const f32x4*)&W[(long)(k0 + r) * 2048 + n0 + c];
        bf16x4 s4 = { f2bs(f[0]), f2bs(f[1]), f2bs(f[2]), f2bs(f[3]) };
        *(bf16x4*)&Tl[r * 68 + c] = s4;
    }
    __syncthreads();
#pragma unroll
    for (int i = 0; i < 4; ++i) {
        const int e = i * 1024 + tid * 4;
        const int nr = e >> 6, kk = e & 63;
        bf16x4 o = { Tl[(kk + 0) * 68 + nr], Tl[(kk + 1) * 68 + nr],
                     Tl[(kk + 2) * 68 + nr], Tl[(kk + 3) * 68 + nr] };
        *(bf16x4*)&out[(long)(n0 + nr) * 2048 + k0 + kk] = o;
    }
}

// ---------------------------------------------------------------------------
// QKV GEMM, 256x256 tile, BK=32, 8 waves, fine-interleaved deep pipeline
// (R12/R14-measured-best). Single barrier per K-step; 32B-granule
// sector-preserving LDS swizzle (conflicts == 0); counted vmcnt(8);
// fused absmax for K/V slices in the epilogue.
// grid 8x8x3 (XCD swizzled): z0 Q bf16*QSCALE, z1/z2 K/V concat remap + amax.
// ---------------------------------------------------------------------------
__global__ __launch_bounds__(512, 2) void gemm_qkv8(
    const short* __restrict__ A,
    const short* __restrict__ Bt0, const short* __restrict__ Bt1, const short* __restrict__ Bt2,
    const float* __restrict__ bi0, const float* __restrict__ bi1, const float* __restrict__ bi2,
    void* __restrict__ o0, void* __restrict__ o1, void* __restrict__ o2,
    float* __restrict__ scal) {
    __shared__ __align__(16) short L[4][16384];   // per buf: A [0,8192), B [8192,16384)

    const int orig = blockIdx.x + 8 * (blockIdx.y + 8 * blockIdx.z);
    int swz = (orig & 7) * 24 + (orig >> 3);      // 192 % 8 == 0
    const int bx = swz & 7; swz >>= 3;
    const int by = swz & 7;
    const int bz = swz >> 3;

    const short* Bt   = bz == 0 ? Bt0 : (bz == 1 ? Bt1 : Bt2);
    const float* bias = bz == 0 ? bi0 : (bz == 1 ? bi1 : bi2);
    void* outp        = bz == 0 ? o0  : (bz == 1 ? o1  : o2);
    const int mode    = (bz == 0) ? 1 : 2;
    const float scl   = (bz == 0) ? QSCALE : 1.f;

    const int tid = threadIdx.x, lane = tid & 63, w = tid >> 6;
    const int wm = w >> 2, wn = w & 3;            // 2(M) x 4(N) waves
    const int l4 = lane >> 4, ln = lane & 15;
    const int m0 = by * 256, n0 = bx * 256;

    // staging: rows {tid>>2, +128}; SOURCE column 32B-granule swizzled
    const int scol = (((tid & 3) ^ (((tid >> 5) & 1) << 1))) * 8;
    const short* gA = A  + (long)(m0 + (tid >> 2)) * 2048 + scol;
    const short* gB = Bt + (long)(n0 + (tid >> 2)) * 2048 + scol;

#define ISSUE_A(t)                                                        \
    do {                                                                  \
        const long ko = (long)(t) * 32;                                   \
        stage16(gA + ko,              &L[(t) & 3][tid * 8]);              \
        stage16(gA + ko + 128 * 2048, &L[(t) & 3][4096 + tid * 8]);       \
    } while (0)
#define ISSUE_B(t)                                                        \
    do {                                                                  \
        const long ko = (long)(t) * 32;                                   \
        stage16(gB + ko,              &L[(t) & 3][8192 + tid * 8]);       \
        stage16(gB + ko + 128 * 2048, &L[(t) & 3][12288 + tid * 8]);      \
    } while (0)

    // read-side slot (same involution; row bit3 at read time = ln bit3)
    const int rsl = (l4 ^ ((ln >> 3) << 1)) * 8;

    f32x4 acc[8][4];
#pragma unroll
    for (int mi = 0; mi < 8; ++mi)
#pragma unroll
        for (int ni = 0; ni < 4; ++ni) acc[mi][ni] = (f32x4){0, 0, 0, 0};

    // prologue: tiles 0,1,2 in flight (12 loads/lane outstanding max)
    ISSUE_A(0); ISSUE_B(0);
    ISSUE_A(1); ISSUE_B(1);
    ISSUE_A(2); ISSUE_B(2);

    for (int t = 0; t < 64; ++t) {
        if (t < 62)       asm volatile("s_waitcnt vmcnt(8)" ::: "memory");
        else if (t == 62) asm volatile("s_waitcnt vmcnt(4)" ::: "memory");
        else              asm volatile("s_waitcnt vmcnt(0)" ::: "memory");
        __builtin_amdgcn_s_barrier();   // tile t visible; buf[(t+3)&3] readers retired
        const int c = t & 3;
        const short* Ab = &L[c][0];
        const short* Bb = &L[c][8192];

        // phase 0: B frags + A frags (mh=0), issue A-stage, 16 MFMA
        bf16x8 bf[4], af[4];
#pragma unroll
        for (int fn = 0; fn < 4; ++fn)
            bf[fn] = *(const bf16x8*)&Bb[(wn * 64 + fn * 16 + ln) * 32 + rsl];
#pragma unroll
        for (int fm = 0; fm < 4; ++fm)
            af[fm] = *(const bf16x8*)&Ab[(wm * 128 + fm * 16 + ln) * 32 + rsl];
        if (t + 3 < 64) ISSUE_A(t + 3);
        __builtin_amdgcn_s_setprio(1);
#pragma unroll
        for (int fm = 0; fm < 4; ++fm)
#pragma unroll
            for (int fn = 0; fn < 4; ++fn)
                acc[fm][fn] = __builtin_amdgcn_mfma_f32_16x16x32_bf16(
                    af[fm], bf[fn], acc[fm][fn], 0, 0, 0);
        __builtin_amdgcn_s_setprio(0);

        // phase 1 (no barrier): A frags (mh=1), issue B-stage, 16 MFMA
        bf16x8 af2[4];
#pragma unroll
        for (int fm = 0; fm < 4; ++fm)
            af2[fm] = *(const bf16x8*)&Ab[(wm * 128 + 64 + fm * 16 + ln) * 32 + rsl];
        if (t + 3 < 64) ISSUE_B(t + 3);
        __builtin_amdgcn_s_setprio(1);
#pragma unroll
        for (int fm = 0; fm < 4; ++fm)
#pragma unroll
            for (int fn = 0; fn < 4; ++fn)
                acc[4 + fm][fn] = __builtin_amdgcn_mfma_f32_16x16x32_bf16(
                    af2[fm], bf[fn], acc[4 + fm][fn], 0, 0, 0);
        __builtin_amdgcn_s_setprio(0);
    }
#undef ISSUE_A
#undef ISSUE_B

    // epilogue + fused absmax (K/V slices)
    float amax = 0.f;
#pragma unroll
    for (int fn = 0; fn < 4; ++fn) {
        const int gn = n0 + wn * 64 + fn * 16 + ln;
        const float bv = bias[gn];
#pragma unroll
        for (int fm = 0; fm < 8; ++fm) {
#pragma unroll
            for (int r = 0; r < 4; ++r) {
                const int gm = m0 + wm * 128 + fm * 16 + l4 * 4 + r;
                const float v = (acc[fm][fn][r] + bv) * scl;
                if (mode == 1) {
                    ((short*)outp)[(long)gm * 2048 + gn] = f2bs(v);
                } else {
                    amax = fmaxf(amax, fabsf(v));
                    const int gr = gm + 1024 + ((gm >> 10) << 10);  // b*2048+1024+s
                    ((short*)outp)[(long)gr * 2048 + gn] = f2bs(v);
                }
            }
        }
    }
    if (mode == 2) {
#pragma unroll
        for (int o = 32; o > 0; o >>= 1) amax = fmaxf(amax, __shfl_xor(amax, o));
        if (lane == 0)
            atomicMax((unsigned int*)&scal[bz - 1], __builtin_bit_cast(unsigned int, amax));
    }
}

// ---------------------------------------------------------------------------
// GEMM (fallback path): R2 structure, 128x128, 2-phase, linear loads.
// mode: 0 = f32 plain, 1 = bf16 plain, 2 = bf16 concat row-remap
// ---------------------------------------------------------------------------
__global__ __launch_bounds__(256, 2) void gemm_m97(
    const short* __restrict__ A, const short* __restrict__ Bt,
    const float* __restrict__ bias, void* __restrict__ outp,
    int mode, float scl) {
    __shared__ __align__(16) short Al[2][4096];
    __shared__ __align__(16) short Bl[2][4096];
    const int nbx = gridDim.x, nby = gridDim.y;
    const int nwg = nbx * nby;
    const int orig = blockIdx.x + nbx * blockIdx.y;
    const int cpx = nwg >> 3;
    int swz = (orig & 7) * cpx + (orig >> 3);
    const int bx = swz % nbx;
    const int by = swz / nbx;

    const int tid = threadIdx.x, lane = tid & 63, w = tid >> 6;
    const int wm = w >> 1, wn = w & 1, l4 = lane >> 4, ln = lane & 15;
    const int m0 = by * 128, n0 = bx * 128;

    const short* gA0 = A  + (long)(m0 + (tid >> 2)) * 2048 + (tid & 3) * 8;
    const short* gA1 = gA0 + 64 * 2048;
    const short* gB0 = Bt + (long)(n0 + (tid >> 2)) * 2048 + (tid & 3) * 8;
    const short* gB1 = gB0 + 64 * 2048;

    f32x4 acc[4][4];
#pragma unroll
    for (int mi = 0; mi < 4; ++mi)
#pragma unroll
        for (int ni = 0; ni < 4; ++ni) acc[mi][ni] = (f32x4){0, 0, 0, 0};

#define STAGE_G(buf, ko)                                   \
    do {                                                   \
        stage16(gA0 + (ko), &Al[buf][tid * 8]);            \
        stage16(gA1 + (ko), &Al[buf][2048 + tid * 8]);     \
        stage16(gB0 + (ko), &Bl[buf][tid * 8]);            \
        stage16(gB1 + (ko), &Bl[buf][2048 + tid * 8]);     \
    } while (0)

    STAGE_G(0, 0);
    asm volatile("s_waitcnt vmcnt(0)" ::: "memory");
    __syncthreads();
    int cur = 0;
    for (int kt = 0; kt < 64; ++kt) {
        if (kt < 63) STAGE_G(cur ^ 1, (kt + 1) * 32);
        bf16x8 af[4], bfr[4];
#pragma unroll
        for (int mi = 0; mi < 4; ++mi)
            af[mi] = *(const bf16x8*)&Al[cur][(wm * 64 + mi * 16 + ln) * 32 + l4 * 8];
#pragma unroll
        for (int ni = 0; ni < 4; ++ni)
            bfr[ni] = *(const bf16x8*)&Bl[cur][(wn * 64 + ni * 16 + ln) * 32 + l4 * 8];
#pragma unroll
        for (int mi = 0; mi < 4; ++mi)
#pragma unroll
            for (int ni = 0; ni < 4; ++ni)
                acc[mi][ni] = __builtin_amdgcn_mfma_f32_16x16x32_bf16(
                    af[mi], bfr[ni], acc[mi][ni], 0, 0, 0);
        asm volatile("s_waitcnt vmcnt(0)" ::: "memory");
        __syncthreads();
        cur ^= 1;
    }
#undef STAGE_G

#pragma unroll
    for (int ni = 0; ni < 4; ++ni) {
        const int gn = n0 + wn * 64 + ni * 16 + ln;
        const float bv = bias[gn];
#pragma unroll
        for (int mi = 0; mi < 4; ++mi) {
#pragma unroll
            for (int r = 0; r < 4; ++r) {
                const int gm = m0 + wm * 64 + mi * 16 + l4 * 4 + r;
                const float v = (acc[mi][ni][r] + bv) * scl;
                if (mode == 0) {
                    ((float*)outp)[(long)gm * 2048 + gn] = v;
                } else if (mode == 1) {
                    ((short*)outp)[(long)gm * 2048 + gn] = f2bs(v);
                } else {
                    const int gr = gm + 1024 + ((gm >> 10) << 10);
                    ((short*)outp)[(long)gr * 2048 + gn] = f2bs(v);
                }
            }
        }
    }
}

// ---------------------------------------------------------------------------
// Wo GEMM: 128(M) x 64(N) tile -> grid 32x16 = 512 blocks = 2 blocks/CU.
// ---------------------------------------------------------------------------
__global__ __launch_bounds__(256, 2) void gemm_wo(const short* __restrict__ A,
                                                  const short* __restrict__ Bt,
                                                  const float* __restrict__ bias,
                                                  float* __restrict__ outp) {
    __shared__ __align__(16) short Al[2][4096];
    __shared__ __align__(16) short Bl[2][2048];
    const int orig = blockIdx.x + 32 * blockIdx.y;
    const int swz = (orig & 7) * 64 + (orig >> 3);   // 512 % 8 == 0
    const int bx = swz & 31, by = swz >> 5;
    const int tid = threadIdx.x, lane = tid & 63, w = tid >> 6;
    const int wm = w >> 1, wn = w & 1, l4 = lane >> 4, ln = lane & 15;
    const int m0 = by * 128, n0 = bx * 64;

    const short* gA0 = A  + (long)(m0 + (tid >> 2)) * 2048 + (tid & 3) * 8;
    const short* gA1 = gA0 + 64 * 2048;
    const short* gB0 = Bt + (long)(n0 + (tid >> 2)) * 2048 + (tid & 3) * 8;

    f32x4 acc[4][2];
#pragma unroll
    for (int mi = 0; mi < 4; ++mi)
#pragma unroll
        for (int ni = 0; ni < 2; ++ni) acc[mi][ni] = (f32x4){0, 0, 0, 0};

#define STAGE_W(buf, ko)                                   \
    do {                                                   \
        stage16(gA0 + (ko), &Al[buf][tid * 8]);            \
        stage16(gA1 + (ko), &Al[buf][2048 + tid * 8]);     \
        stage16(gB0 + (ko), &Bl[buf][tid * 8]);            \
    } while (0)

    STAGE_W(0, 0);
    asm volatile("s_waitcnt vmcnt(0)" ::: "memory");
    __syncthreads();
    int cur = 0;
    for (int kt = 0; kt < 64; ++kt) {
        if (kt < 63) STAGE_W(cur ^ 1, (kt + 1) * 32);
        bf16x8 af[4], bfr[2];
#pragma unroll
        for (int mi = 0; mi < 4; ++mi)
            af[mi] = *(const bf16x8*)&Al[cur][(wm * 64 + mi * 16 + ln) * 32 + l4 * 8];
#pragma unroll
        for (int ni = 0; ni < 2; ++ni)
            bfr[ni] = *(const bf16x8*)&Bl[cur][(wn * 32 + ni * 16 + ln) * 32 + l4 * 8];
#pragma unroll
        for (int mi = 0; mi < 4; ++mi)
#pragma unroll
            for (int ni = 0; ni < 2; ++ni)
                acc[mi][ni] = __builtin_amdgcn_mfma_f32_16x16x32_bf16(
                    af[mi], bfr[ni], acc[mi][ni], 0, 0, 0);
        asm volatile("s_waitcnt vmcnt(0)" ::: "memory");
        __syncthreads();
        cur ^= 1;
    }
#undef STAGE_W

#pragma unroll
    for (int ni = 0; ni < 2; ++ni) {
        const int gn = n0 + wn * 32 + ni * 16 + ln;
        const float bv = bias[gn];
#pragma unroll
        for (int mi = 0; mi < 4; ++mi) {
#pragma unroll
            for (int r = 0; r < 4; ++r) {
                const int gm = m0 + wm * 64 + mi * 16 + l4 * 4 + r;
                outp[(long)gm * 2048 + gn] = acc[mi][ni][r] + bv;
            }
        }
    }
}

// ---------------------------------------------------------------------------
// absmax (fallback path only)
// ---------------------------------------------------------------------------
__global__ void absmax_kernel(const short* __restrict__ Kf, const short* __restrict__ Vf,
                              float* __restrict__ scal) {
    const int z = blockIdx.z;
    const short* src = z ? Vf : Kf;
    const int tid = threadIdx.x, lane = tid & 63, w = tid >> 6;
    float mx = 0.f;
    const int stride = gridDim.x * blockDim.x;
    for (int i = blockIdx.x * blockDim.x + tid; i < NELEM / 8; i += stride) {
        const int e = i * 8;
        const int flat = e + 2097152 + ((e >> 21) << 21);
        bf16x8 v = *(const bf16x8*)&src[flat];
#pragma unroll
        for (int j = 0; j < 8; ++j) mx = fmaxf(mx, fabsf(bs2f(v[j])));
    }
#pragma unroll
    for (int o = 32; o > 0; o >>= 1) mx = fmaxf(mx, __shfl_xor(mx, o));
    __shared__ float wred[4];
    if (lane == 0) wred[w] = mx;
    __syncthreads();
    if (tid == 0) {
        const float m2 = fmaxf(fmaxf(wred[0], wred[1]), fmaxf(wred[2], wred[3]));
        atomicMax((unsigned int*)&scal[z], __builtin_bit_cast(unsigned int, m2));
    }
}

// ---------------------------------------------------------------------------
// quantize new-KV region -> d_out (as floats), plus the two scale scalars
// (x8 vectorized)
// ---------------------------------------------------------------------------
__global__ void quantize_kernel(const short* __restrict__ Kf, const short* __restrict__ Vf,
                                const float* __restrict__ scal, float* __restrict__ out) {
    const int z = blockIdx.z;
    const short* src = z ? Vf : Kf;
    const float mx = scal[z];
    const float scale = mx * (1.f / 127.f);
    const float inv = (mx > 0.f) ? 127.f / mx : 0.f;
    const long ob = z ? (2L * BSD + 1) : (1L * BSD);
    if (blockIdx.x == 0 && threadIdx.x == 0)
        out[z ? (3L * BSD + 1) : (2L * BSD)] = scale;
    const int stride = gridDim.x * blockDim.x;
    for (int i = blockIdx.x * blockDim.x + threadIdx.x; i < NELEM / 8; i += stride) {
        const int e = i * 8;
        const int flat = e + 2097152 + ((e >> 21) << 21);
        bf16x8 x8 = *(const bf16x8*)&src[flat];
        float4 q0, q1;
        q0.x = fminf(127.f, fmaxf(-128.f, rintf(bs2f(x8[0]) * inv)));
        q0.y = fminf(127.f, fmaxf(-128.f, rintf(bs2f(x8[1]) * inv)));
        q0.z = fminf(127.f, fmaxf(-128.f, rintf(bs2f(x8[2]) * inv)));
        q0.w = fminf(127.f, fmaxf(-128.f, rintf(bs2f(x8[3]) * inv)));
        q1.x = fminf(127.f, fmaxf(-128.f, rintf(bs2f(x8[4]) * inv)));
        q1.y = fminf(127.f, fmaxf(-128.f, rintf(bs2f(x8[5]) * inv)));
        q1.z = fminf(127.f, fmaxf(-128.f, rintf(bs2f(x8[6]) * inv)));
        q1.w = fminf(127.f, fmaxf(-128.f, rintf(bs2f(x8[7]) * inv)));
        *(float4*)&out[ob + e] = q0;
        *(float4*)&out[ob + e + 4] = q1;
    }
}

// ---------------------------------------------------------------------------
// flash attention, double-buffered LDS, exp2-domain softmax (Q pre-scaled by
// SOFT_SCALE*log2e in the Q GEMM; exp -> exp2f = bare v_exp_f32).
// R14-measured-best attn structure (T15 double-pipeline measured -60%).
// ---------------------------------------------------------------------------
__global__ __launch_bounds__(256, 2) void attn_kernel(const short* __restrict__ Q,
                                                      const short* __restrict__ Kf,
                                                      const short* __restrict__ Vf,
                                                      short* __restrict__ O) {
    __shared__ __align__(16) short Kl[2][64 * 136];   // 34.0 KB
    __shared__ __align__(16) short Vt[2][128 * 72];   // 36.0 KB
    const int L = blockIdx.x + 16 * (blockIdx.y + 16 * blockIdx.z);
    const int x = L & 7, rr = L >> 3;
    const int qt0 = rr & 15, pgrp = rr >> 4;
    const int p = x + 8 * pgrp;
    const int h = p >> 1, b = p & 1;
    const int qt = (pgrp >= 2) ? (15 - qt0) : qt0;

    const int tid = threadIdx.x, w = tid >> 6, lane = tid & 63;
    const int l4 = lane >> 4, n = lane & 15;
    const int rg = tid >> 4, cg = tid & 15, stc = cg * 8;
    const int sIdx = qt * 64 + w * 16 + n;
    const int qlim = 1024 + sIdx;

    bf16x8 qf[4];
#pragma unroll
    for (int c = 0; c < 4; ++c)
        qf[c] = *(const bf16x8*)&Q[(long)(b * 1024 + sIdx) * 2048 + h * 128 + c * 32 + l4 * 8];

    f32x4 acco[8];
#pragma unroll
    for (int i = 0; i < 8; ++i) acco[i] = (f32x4){0, 0, 0, 0};
    float m_run = 0.f, l_run = 0.f;

    const short* Kb = Kf + (long)(b * 2048) * 2048 + h * 128;
    const short* Vb = Vf + (long)(b * 2048) * 2048 + h * 128;
    const int nt = 17 + qt;

    bf16x8 kreg[4], vreg[4];
#define LOAD_KV(te)                                                                   \
    do {                                                                              \
        _Pragma("unroll")                                                             \
        for (int i = 0; i < 4; ++i)                                                   \
            kreg[i] = *(const bf16x8*)&Kb[(long)((te) + i * 16 + rg) * 2048 + stc];   \
        _Pragma("unroll")                                                             \
        for (int i = 0; i < 4; ++i)                                                   \
            vreg[i] = *(const bf16x8*)&Vb[(long)((te) + rg * 4 + i) * 2048 + stc];    \
    } while (0)
#define WRITE_BUF(bf)                                                                 \
    do {                                                                              \
        _Pragma("unroll")                                                             \
        for (int i = 0; i < 4; ++i)                                                   \
            *(bf16x8*)&Kl[bf][(i * 16 + rg) * 136 + stc] = kreg[i];                   \
        _Pragma("unroll")                                                             \
        for (int j = 0; j < 8; ++j) {                                                 \
            const int d = stc + j;                                                    \
            bf16x4 c4 = { vreg[0][j], vreg[1][j], vreg[2][j], vreg[3][j] };           \
            *(bf16x4*)&Vt[bf][d * 72 + ((rg ^ ((d >> 3) & 7)) << 2)] = c4;            \
        }                                                                             \
    } while (0)

    LOAD_KV(0);
    WRITE_BUF(0);
    __syncthreads();

    for (int t = 0; t < nt; ++t) {
        const int buf = t & 1;
        const int t0 = t * 64;
        if (t + 1 < nt) LOAD_KV((t + 1) * 64);

        float p16[16];
        __builtin_amdgcn_s_setprio(1);
#pragma unroll
        for (int kt = 0; kt < 4; ++kt) {
            f32x4 sc4 = (f32x4){0, 0, 0, 0};
#pragma unroll
            for (int c = 0; c < 4; ++c) {
                bf16x8 kfr = *(const bf16x8*)&Kl[buf][(kt * 16 + n) * 136 + c * 32 + l4 * 8];
                sc4 = __builtin_amdgcn_mfma_f32_16x16x32_bf16(kfr, qf[c], sc4, 0, 0, 0);
            }
#pragma unroll
            for (int r = 0; r < 4; ++r) p16[kt * 4 + r] = sc4[r];
        }
        __builtin_amdgcn_s_setprio(0);
        if (t >= 16) {
#pragma unroll
            for (int i = 0; i < 16; ++i) {
                const int kg = t0 + (i >> 2) * 16 + l4 * 4 + (i & 3);
                if (kg > qlim) p16[i] = -1e30f;
            }
        }

        float tmax = fmaxf(p16[0], p16[1]);
#pragma unroll
        for (int i = 2; i < 16; ++i) tmax = fmaxf(tmax, p16[i]);
        tmax = fmaxf(tmax, __shfl_xor(tmax, 16));
        tmax = fmaxf(tmax, __shfl_xor(tmax, 32));
        float e16[16], ps[4] = {0.f, 0.f, 0.f, 0.f};
#pragma unroll
        for (int i = 0; i < 16; ++i) { e16[i] = exp2f(p16[i] - m_run); ps[i & 3] += e16[i]; }
        float tsum = (ps[0] + ps[1]) + (ps[2] + ps[3]);
        if (!__all(tmax <= m_run + DEFER_THR)) {
            const float mnew = fmaxf(m_run, tmax);
            const float fac = exp2f(m_run - mnew);
            tsum *= fac;
#pragma unroll
            for (int i = 0; i < 16; ++i) e16[i] *= fac;
            l_run *= fac;
#pragma unroll
            for (int i = 0; i < 8; ++i) acco[i] *= fac;
            m_run = mnew;
        }
        tsum += __shfl_xor(tsum, 16);
        tsum += __shfl_xor(tsum, 32);
        l_run += tsum;

        u32x4 pw0, pw1;
#pragma unroll
        for (int wd = 0; wd < 4; ++wd) {
            unsigned r0, r1;
            asm("v_cvt_pk_bf16_f32 %0, %1, %2" : "=v"(r0) : "v"(e16[2 * wd]), "v"(e16[2 * wd + 1]));
            asm("v_cvt_pk_bf16_f32 %0, %1, %2" : "=v"(r1) : "v"(e16[8 + 2 * wd]), "v"(e16[8 + 2 * wd + 1]));
            pw0[wd] = r0; pw1[wd] = r1;
        }
        bf16x8 pb[2] = { __builtin_bit_cast(bf16x8, pw0), __builtin_bit_cast(bf16x8, pw1) };

        __builtin_amdgcn_s_setprio(1);
#pragma unroll
        for (int dc = 0; dc < 8; ++dc) {
            const int d = dc * 16 + n;
            const int swd = ((d >> 3) & 7) << 2;
#pragma unroll
            for (int k32 = 0; k32 < 2; ++k32) {
                bf16x4 g0 = *(const bf16x4*)&Vt[buf][d * 72 + (k32 * 32 + ((4 * l4) ^ swd))];
                bf16x4 g1 = *(const bf16x4*)&Vt[buf][d * 72 + (k32 * 32 + ((16 + 4 * l4) ^ swd))];
                bf16x8 vf = { g0[0], g0[1], g0[2], g0[3], g1[0], g1[1], g1[2], g1[3] };
                acco[dc] = __builtin_amdgcn_mfma_f32_16x16x32_bf16(vf, pb[k32], acco[dc], 0, 0, 0);
            }
        }
        __builtin_amdgcn_s_setprio(0);

        if (t + 1 < nt) WRITE_BUF(buf ^ 1);
        __syncthreads();
    }
#undef LOAD_KV
#undef WRITE_BUF

    const float inv = 1.f / l_run;
#pragma unroll
    for (int dc = 0; dc < 8; ++dc)
#pragma unroll
        for (int r = 0; r < 4; ++r)
            Kl[0][(w * 16 + n) * 136 + dc * 16 + l4 * 4 + r] = f2bs(acco[dc][r] * inv);
    __syncthreads();
#pragma unroll
    for (int i = 0; i < 4; ++i) {
        const int row = i * 4 + (lane >> 4);
        const int col = (lane & 15) * 8;
        bf16x8 ov = *(const bf16x8*)&Kl[0][(w * 16 + row) * 136 + col];
        *(bf16x8*)&O[(long)(b * 1024 + qt * 64 + w * 16 + row) * 2048 + h * 128 + col] = ov;
    }
}

// ---------------------------------------------------------------------------
extern "C" void kernel_launch(void* const* d_in, const int* in_sizes, int n_in,
                              void* d_out, int out_size, void* d_ws, size_t ws_size,
                              hipStream_t stream) {
    const float* h   = (const float*)d_in[0];
    const float* Wq  = (const float*)d_in[1];
    const float* bq  = (const float*)d_in[2];
    const float* Wk  = (const float*)d_in[3];
    const float* bk  = (const float*)d_in[4];
    const float* Wv  = (const float*)d_in[5];
    const float* bv  = (const float*)d_in[6];
    const float* Wo  = (const float*)d_in[7];
    const float* bo  = (const float*)d_in[8];
    const void*  pkq = d_in[9];
    const float* pks = (const float*)d_in[10];
    const void*  pvq = d_in[11];
    const float* pvs = (const float*)d_in[12];
    float* out = (float*)d_out;

    char* ws = (char*)d_ws;
    dim3 blk(256);

    if (ws_size >= 83886336ull) {
        float* scal  = (float*)ws;
        short* hbf   = (short*)(ws + 256);
        short* WT4   = (short*)(ws + 256 + 1L * 8388608);
        short* Qbf   = (short*)(ws + 256 + 5L * 8388608);
        short* Kfull = (short*)(ws + 256 + 6L * 8388608);
        short* Vfull = (short*)(ws + 256 + 6L * 8388608 + 16777216);
        short* attnb = hbf;

        probe_init<<<1, 64, 0, stream>>>((const int*)pkq, scal);
        prep_kernel<<<dim3(256, 1, 3), blk, 0, stream>>>(h, hbf, pkq, pvq, pks, pvs,
                                                         Kfull, Vfull, (const int*)d_ws);
        transpose_conv<<<dim3(32, 32, 4), blk, 0, stream>>>(Wq, Wk, Wv, Wo, WT4);
        gemm_qkv8<<<dim3(8, 8, 3), dim3(512), 0, stream>>>(hbf, WT4, WT4 + 4194304,
                                                           WT4 + 8388608, bq, bk, bv,
                                                           Qbf, Kfull, Vfull, scal);
        quantize_kernel<<<dim3(256, 1, 2), blk, 0, stream>>>(Kfull, Vfull, scal, out);
        attn_kernel<<<dim3(16, 16, 2), blk, 0, stream>>>(Qbf, Kfull, Vfull, attnb);
        gemm_wo<<<dim3(32, 16), blk, 0, stream>>>(attnb, WT4 + 12582912, bo, out);
    } else {
        float* scal  = (float*)ws;
        short* hbf   = (short*)(ws + 256);
        short* WT    = (short*)(ws + 256 + 1L * 8388608);
        short* Qbf   = (short*)(ws + 256 + 2L * 8388608);
        short* Kfull = (short*)(ws + 256 + 3L * 8388608);
        short* Vfull = (short*)(ws + 256 + 3L * 8388608 + 16777216);
        short* attnb = hbf;

        probe_init<<<1, 64, 0, stream>>>((const int*)pkq, scal);
        prep_kernel<<<dim3(256, 1, 3), blk, 0, stream>>>(h, hbf, pkq, pvq, pks, pvs,
                                                         Kfull, Vfull, (const int*)d_ws);
        transpose_conv<<<dim3(32, 32, 1), blk, 0, stream>>>(Wk, Wk, Wk, Wk, WT);
        gemm_m97<<<dim3(16, 16), blk, 0, stream>>>(hbf, WT, bk, Kfull, 2, 1.f);
        transpose_conv<<<dim3(32, 32, 1), blk, 0, stream>>>(Wv, Wv, Wv, Wv, WT);
        gemm_m97<<<dim3(16, 16), blk, 0, stream>>>(hbf, WT, bv, Vfull, 2, 1.f);
        absmax_kernel<<<dim3(512, 1, 2), blk, 0, stream>>>(Kfull, Vfull, scal);
        quantize_kernel<<<dim3(256, 1, 2), blk, 0, stream>>>(Kfull, Vfull, scal, out);
        transpose_conv<<<dim3(32, 32, 1), blk, 0, stream>>>(Wq, Wq, Wq, Wq, WT);
        gemm_m97<<<dim3(16, 16), blk, 0, stream>>>(hbf, WT, bq, Qbf, 1, QSCALE);
        attn_kernel<<<dim3(16, 16, 2), blk, 0, stream>>>(Qbf, Kfull, Vfull, attnb);
        transpose_conv<<<dim3(32, 32, 1), blk, 0, stream>>>(Wo, Wo, Wo, Wo, WT);
        gemm_wo<<<dim3(32, 16), blk, 0, stream>>>(attnb, WT, bo, out);
    }
}